// Round 11
// baseline (507.403 us; speedup 1.0000x reference)
//
#include <hip/hip_runtime.h>
#include <hip/hip_fp16.h>
#include <cmath>

#define IN_DIM 256
#define HID 128
#define HID2 64
#define SB 512        // bin-role blocks in the fused kernel
#define NODES_PB 256  // nodes per bucket (bin path)
#define NBKT_MAX 448  // max buckets supported by LDS scan arrays
#define BCAP 9216     // records per bucket region (mean 8184 + 11 sigma)
#define CHB 2048      // chunk size for bin-role in-LDS counting sort
#define CH 4096       // chunk size for bucket_build counting sort
#define SMEM_BIN (4 * NBKT_MAX * 4 + CHB * 9)  // 7168 + 18432 = 25600

struct __align__(8) EdgeP { int s; float w; };
union H4 { __half h[4]; uint2 u; };
union H2 { __half2 h2; uint u; };

using f16x8 = __attribute__((ext_vector_type(8))) _Float16;
using f32x4 = __attribute__((ext_vector_type(4))) float;

__device__ __forceinline__ float selu_f(float x) {
    const float scale = 1.0507009873554805f;
    const float alpha = 1.6732632423543772f;
    return x > 0.f ? scale * x : scale * alpha * expm1f(x);
}

// ---------------- small utility kernels ----------------

__global__ void zero_ints(int* p, int n) {
    int i = blockIdx.x * blockDim.x + threadIdx.x;
    if (i < n) p[i] = 0;
}

// WT[c][k] fp16 from B1 (K x C1) | B2 (K x C2); one block per output col c.
__global__ void transpose_w(const float* __restrict__ B1, const float* __restrict__ B2,
                            __half* __restrict__ WT, int K, int C1, int C2) {
    int c = blockIdx.x;
    for (int k = threadIdx.x; k < K; k += blockDim.x) {
        float v = (c < C1) ? B1[(size_t)k * C1 + c] : B2[(size_t)k * C2 + (c - C1)];
        WT[(size_t)c * K + k] = __float2half(v);
    }
}

// ---- fallback-path degree+dinv (one wave per node over ELL) ----
__global__ void deg_dinv(const EdgeP* __restrict__ ell, int* cnt, float* dinv, int n, int cap) {
    int wid = (blockIdx.x * blockDim.x + threadIdx.x) >> 6;
    int lane = threadIdx.x & 63;
    if (wid >= n) return;
    size_t base = (size_t)wid * cap;
    int len = min(cnt[wid], cap);
    float s = 0.f;
    for (int i = lane; i < len; i += 64) s += ell[base + i].w;
#pragma unroll
    for (int o = 32; o; o >>= 1) s += __shfl_xor(s, o);
    if (lane == 0) {
        dinv[wid] = rsqrtf(s + 1.0f);  // +1 = self-loop weight
        cnt[wid] = len;
    }
}

// exclusive scan of lds_in[0..nb) -> lds_out, executed by wave 0 (tid<64). nb <= 64*PER.
template <int PER>
__device__ __forceinline__ void wave0_excl_scan(const int* lds_in, int* lds_out, int nb, int tid) {
    if (tid < 64) {
        int r[PER];
        int sum = 0;
#pragma unroll
        for (int k = 0; k < PER; ++k) {
            int idx = tid * PER + k;
            int v = (idx < nb) ? lds_in[idx] : 0;
            r[k] = sum;
            sum += v;
        }
        int run = sum;
#pragma unroll
        for (int o = 1; o < 64; o <<= 1) {
            int t = __shfl_up(run, o);
            if (tid >= o) run += t;
        }
        int excl = run - sum;
#pragma unroll
        for (int k = 0; k < PER; ++k) {
            int idx = tid * PER + k;
            if (idx < nb) lds_out[idx] = excl + r[k];
        }
    }
}

// ---------------- fused role-split kernel ----------------
// Blocks [0,sblocks): bin role, mode=1: ONE global-atomic reserve per (block,bucket)
// (full-range LDS hist first), then per-chunk in-LDS counting sort by bucket and
// coalesced dump of (s<<8|dstLocal, w) records with a running LDS cursor gwcur[b].
// mode=0: direct ELL scatter fallback. Remaining blocks: layer-0 GEMM via f16 MFMA.
__global__ __launch_bounds__(256) void bin_gemm0(
    const float* __restrict__ A, const __half* __restrict__ WT,
    const float* __restrict__ bias1, const float* __restrict__ bias2,
    __half* __restrict__ outA, float* __restrict__ outB, int M,
    const int* __restrict__ ei, const float* __restrict__ ew,
    int* cnt_or_bcur, EdgeP* __restrict__ dst_buf,
    int E, int cap, int epb, int sblocks, int nb, int mode) {
    const int tid = threadIdx.x;
    // union LDS: bin role 25600B; GEMM role 2*128*40*2 = 20480B.
    __shared__ __align__(16) char smem[SMEM_BIN];

    if ((int)blockIdx.x < sblocks) {
        int lo = blockIdx.x * epb;
        int hi = min(E, lo + epb);
        if (mode == 1) {
            int* gwcur = (int*)smem;                    // [NBKT_MAX] running global cursor
            int* chist = gwcur + NBKT_MAX;              // [NBKT_MAX]
            int* coff = chist + NBKT_MAX;               // [NBKT_MAX]
            int* ccur = coff + NBKT_MAX;                // [NBKT_MAX]
            int* sortedS = ccur + NBKT_MAX;             // [CHB] key: bit25=b>>8, bits8..24=s, 0..7=dl
            float* sortedW = (float*)(sortedS + CHB);   // [CHB]
            unsigned char* smap = (unsigned char*)(sortedW + CHB);  // [CHB] low 8 bits of b

            // phase A: full-range hist -> one reserve per bucket
            for (int i = tid; i < nb; i += 256) chist[i] = 0;
            __syncthreads();
            for (int e = lo + tid; e < hi; e += 256)
                atomicAdd(&chist[ei[E + e] >> 8], 1);
            __syncthreads();
            for (int b = tid; b < nb; b += 256) {
                int h = chist[b];
                gwcur[b] = h ? atomicAdd(&cnt_or_bcur[b], h) : 0;
            }
            __syncthreads();

            // phase B: per-chunk counting sort + coalesced dump
            for (int c0 = lo; c0 < hi; c0 += CHB) {
                int cn = min(CHB, hi - c0);
                for (int i = tid; i < nb; i += 256) chist[i] = 0;
                __syncthreads();
                for (int r = tid; r < cn; r += 256)
                    atomicAdd(&chist[ei[E + c0 + r] >> 8], 1);
                __syncthreads();
                wave0_excl_scan<7>(chist, coff, nb, tid);
                __syncthreads();
                for (int b = tid; b < nb; b += 256) ccur[b] = coff[b];
                __syncthreads();
                for (int r = tid; r < cn; r += 256) {
                    int e = c0 + r;
                    int d = ei[E + e];
                    int b = d >> 8;
                    int slot = atomicAdd(&ccur[b], 1);
                    sortedS[slot] = (ei[e] << 8) | (d & 255) | ((b >> 8) << 25);
                    sortedW[slot] = ew[e];
                    smap[slot] = (unsigned char)(b & 255);
                }
                __syncthreads();
                for (int i = tid; i < cn; i += 256) {
                    int key = sortedS[i];
                    int b = smap[i] | (((key >> 25) & 1) << 8);
                    int addr = gwcur[b] + (i - coff[b]);
                    if (addr < BCAP) {
                        EdgeP p; p.s = key & 0x01FFFFFF; p.w = sortedW[i];
                        dst_buf[(size_t)b * BCAP + addr] = p;
                    }
                }
                __syncthreads();
                for (int b = tid; b < nb; b += 256) gwcur[b] += chist[b];
                __syncthreads();
            }
        } else {
            for (int base = lo; base < hi; base += 2048) {
                int r[8], c[8], pos[8];
                float wv[8];
#pragma unroll
                for (int j = 0; j < 8; ++j) {
                    int e = base + j * 256 + tid;
                    c[j] = -1;
                    if (e < hi) { r[j] = ei[e]; c[j] = ei[E + e]; wv[j] = ew[e]; }
                }
#pragma unroll
                for (int j = 0; j < 8; ++j)
                    if (c[j] >= 0) pos[j] = atomicAdd(&cnt_or_bcur[c[j]], 1);
#pragma unroll
                for (int j = 0; j < 8; ++j)
                    if (c[j] >= 0 && pos[j] < cap) {
                        EdgeP p; p.s = r[j]; p.w = wv[j];
                        dst_buf[(size_t)c[j] * cap + pos[j]] = p;
                    }
            }
        }
        return;
    }

    // ---- MFMA GEMM role: K=256 ----
    __half* sA16 = (__half*)smem;            // [128*40]
    __half* sB16 = (__half*)(smem + 10240);  // [128*40]
    const int bid = blockIdx.x - sblocks;
    const int m0 = (bid >> 1) * 128;
    const int n0 = (bid & 1) * 128;
    const int lane = tid & 63;
    const int wv = tid >> 6;
    const int wr = (wv >> 1) * 64;
    const int wc = (wv & 1) * 64;
    const int lr = lane & 15, lk = lane >> 4;

    f32x4 zero = {0.f, 0.f, 0.f, 0.f};
    f32x4 acc[4][4];
#pragma unroll
    for (int i = 0; i < 4; ++i)
#pragma unroll
        for (int j = 0; j < 4; ++j) acc[i][j] = zero;

    for (int k0 = 0; k0 < IN_DIM; k0 += 32) {
#pragma unroll
        for (int p = 0; p < 4; ++p) {
            int f4 = p * 256 + tid;
            int r = f4 >> 3;
            int kk = (f4 & 7) << 2;
            int row = m0 + r;
            float4 v = make_float4(0.f, 0.f, 0.f, 0.f);
            if (row < M) v = *(const float4*)(A + (size_t)row * IN_DIM + k0 + kk);
            H4 h;
            h.h[0] = __float2half(v.x); h.h[1] = __float2half(v.y);
            h.h[2] = __float2half(v.z); h.h[3] = __float2half(v.w);
            *(uint2*)&sA16[r * 40 + kk] = h.u;
        }
#pragma unroll
        for (int p = 0; p < 2; ++p) {
            int f = p * 256 + tid;
            int c = f >> 2;
            int kc = (f & 3) << 3;
            *(uint4*)&sB16[c * 40 + kc] =
                *(const uint4*)(WT + (size_t)(n0 + c) * IN_DIM + k0 + kc);
        }
        __syncthreads();
        f16x8 af[4], bf[4];
#pragma unroll
        for (int i = 0; i < 4; ++i)
            af[i] = *(const f16x8*)&sA16[(wr + i * 16 + lr) * 40 + lk * 8];
#pragma unroll
        for (int j = 0; j < 4; ++j)
            bf[j] = *(const f16x8*)&sB16[(wc + j * 16 + lr) * 40 + lk * 8];
#pragma unroll
        for (int i = 0; i < 4; ++i)
#pragma unroll
            for (int j = 0; j < 4; ++j)
                acc[i][j] = __builtin_amdgcn_mfma_f32_16x16x32_f16(af[i], bf[j], acc[i][j], 0, 0, 0);
        __syncthreads();
    }

    float bs[4];
    if (n0 != 0) {
#pragma unroll
        for (int j = 0; j < 4; ++j) {
            int c = wc + j * 16 + lr;
            bs[j] = bias1[c] + bias2[c];
        }
    }
#pragma unroll
    for (int i = 0; i < 4; ++i) {
        int rowb = m0 + wr + i * 16 + lk * 4;
#pragma unroll
        for (int j = 0; j < 4; ++j) {
            int col = wc + j * 16 + lr;
#pragma unroll
            for (int r = 0; r < 4; ++r) {
                int row = rowb + r;
                if (row < M) {
                    if (n0 == 0)
                        outA[(size_t)row * HID + col] = __float2half(acc[i][j][r]);
                    else
                        outB[(size_t)row * HID + col] = acc[i][j][r] + bs[j];
                }
            }
        }
    }
}

// ---------------- phase-2: per-bucket ELL build via in-LDS counting sort by node ----------------
__global__ __launch_bounds__(256) void bucket_build(
    const EdgeP* __restrict__ recs, const int* __restrict__ bcur,
    EdgeP* __restrict__ ell, int* __restrict__ cnt, float* __restrict__ dinv,
    int n, int cap) {
    __shared__ int lcnt[NODES_PB];      // running per-node count across chunks
    __shared__ float ldeg[NODES_PB];
    __shared__ int chist[NODES_PB];
    __shared__ int coff[NODES_PB];
    __shared__ int ccur[NODES_PB];
    __shared__ __align__(8) int sortedS[CH];
    __shared__ float sortedW[CH];
    __shared__ unsigned char cmap[CH];
    int b = blockIdx.x, tid = threadIdx.x;
    lcnt[tid] = 0;
    ldeg[tid] = 0.f;
    __syncthreads();
    int m = min(bcur[b], BCAP);
    const EdgeP* rbase = recs + (size_t)b * BCAP;
    for (int c0 = 0; c0 < m; c0 += CH) {
        int cn = min(CH, m - c0);
        chist[tid] = 0;
        __syncthreads();
        for (int i = tid; i < cn; i += 256) {
            EdgeP p = rbase[c0 + i];
            int dl = p.s & 255;
            atomicAdd(&chist[dl], 1);
            atomicAdd(&ldeg[dl], p.w);
        }
        __syncthreads();
        wave0_excl_scan<4>(chist, coff, NODES_PB, tid);
        __syncthreads();
        ccur[tid] = coff[tid];
        __syncthreads();
        for (int i = tid; i < cn; i += 256) {
            EdgeP p = rbase[c0 + i];
            int dl = p.s & 255;
            int slot = atomicAdd(&ccur[dl], 1);
            sortedS[slot] = p.s >> 8;   // unpacked src
            sortedW[slot] = p.w;
            cmap[slot] = (unsigned char)dl;
        }
        __syncthreads();
        for (int i = tid; i < cn; i += 256) {
            int dl = cmap[i];
            int rank = lcnt[dl] + (i - coff[dl]);
            if (rank < cap) {
                EdgeP q; q.s = sortedS[i]; q.w = sortedW[i];
                ell[((size_t)(b * NODES_PB + dl)) * cap + rank] = q;
            }
        }
        __syncthreads();
        lcnt[tid] += chist[tid];
        __syncthreads();
    }
    int v = b * NODES_PB + tid;
    if (v < n) {
        cnt[v] = min(lcnt[tid], cap);
        dinv[v] = rsqrtf(ldeg[tid] + 1.0f);
    }
}

// ---------------- layer-1 GEMM via f16 MFMA ----------------
__global__ __launch_bounds__(256) void gemm1_fused(
    const float* __restrict__ A, const __half* __restrict__ WT,
    const float* __restrict__ bias1, const float* __restrict__ bias2,
    __half* __restrict__ outA, float* __restrict__ outB, int M) {
    const int tid = threadIdx.x;
    __shared__ __align__(16) __half sA16[128 * 40];
    __shared__ __align__(16) __half sB16[128 * 40];
    const int m0 = blockIdx.x * 128;
    const int lane = tid & 63;
    const int wv = tid >> 6;
    const int wr = (wv >> 1) * 64;
    const int wc = (wv & 1) * 64;
    const int lr = lane & 15, lk = lane >> 4;

    f32x4 zero = {0.f, 0.f, 0.f, 0.f};
    f32x4 acc[4][4];
#pragma unroll
    for (int i = 0; i < 4; ++i)
#pragma unroll
        for (int j = 0; j < 4; ++j) acc[i][j] = zero;

    for (int k0 = 0; k0 < HID; k0 += 32) {
#pragma unroll
        for (int p = 0; p < 4; ++p) {
            int f4 = p * 256 + tid;
            int r = f4 >> 3;
            int kk = (f4 & 7) << 2;
            int row = m0 + r;
            float4 v = make_float4(0.f, 0.f, 0.f, 0.f);
            if (row < M) v = *(const float4*)(A + (size_t)row * HID + k0 + kk);
            H4 h;
            h.h[0] = __float2half(v.x); h.h[1] = __float2half(v.y);
            h.h[2] = __float2half(v.z); h.h[3] = __float2half(v.w);
            *(uint2*)&sA16[r * 40 + kk] = h.u;
        }
#pragma unroll
        for (int p = 0; p < 2; ++p) {
            int f = p * 256 + tid;
            int c = f >> 2;
            int kc = (f & 3) << 3;
            *(uint4*)&sB16[c * 40 + kc] =
                *(const uint4*)(WT + (size_t)c * HID + k0 + kc);
        }
        __syncthreads();
        f16x8 af[4], bf[4];
#pragma unroll
        for (int i = 0; i < 4; ++i)
            af[i] = *(const f16x8*)&sA16[(wr + i * 16 + lr) * 40 + lk * 8];
#pragma unroll
        for (int j = 0; j < 4; ++j)
            bf[j] = *(const f16x8*)&sB16[(wc + j * 16 + lr) * 40 + lk * 8];
#pragma unroll
        for (int i = 0; i < 4; ++i)
#pragma unroll
            for (int j = 0; j < 4; ++j)
                acc[i][j] = __builtin_amdgcn_mfma_f32_16x16x32_f16(af[i], bf[j], acc[i][j], 0, 0, 0);
        __syncthreads();
    }

    float bs[4];
    if (wc != 0) {
#pragma unroll
        for (int j = 0; j < 4; ++j) {
            int c = wc + j * 16 + lr - HID2;
            bs[j] = bias1[c] + bias2[c];
        }
    }
#pragma unroll
    for (int i = 0; i < 4; ++i) {
        int rowb = m0 + wr + i * 16 + lk * 4;
#pragma unroll
        for (int j = 0; j < 4; ++j) {
            int col = wc + j * 16 + lr;
#pragma unroll
            for (int r = 0; r < 4; ++r) {
                int row = rowb + r;
                if (row < M) {
                    if (wc == 0)
                        outA[(size_t)row * HID2 + col] = __float2half(acc[i][j][r]);
                    else
                        outB[(size_t)row * HID2 + (col - HID2)] = acc[i][j][r] + bs[j];
                }
            }
        }
    }
}

// ---------------- aggregation F=128: ONE WAVE per node, half2 per lane, ILP-8 ----------------
__global__ __launch_bounds__(256) void aggregate128(
    const __half* __restrict__ hW, float* __restrict__ S,
    const float* __restrict__ dinv, const int* __restrict__ cnt,
    const EdgeP* __restrict__ ell, int cap, int n) {
    int v = (blockIdx.x * 256 + threadIdx.x) >> 6;
    int lane = threadIdx.x & 63;
    if (v >= n) return;
    float di = dinv[v];
    float2 sv = *(const float2*)&S[(size_t)v * HID + lane * 2];
    H2 selfh; selfh.u = *(const uint*)&hW[(size_t)v * HID + lane * 2];
    float2 selff = __half22float2(selfh.h2);
    float selfx = sv.x + di * di * selff.x;
    float selfy = sv.y + di * di * selff.y;

    size_t base = (size_t)v * cap;
    int len = cnt[v];
    float ax[4] = {0.f, 0.f, 0.f, 0.f};
    float ay[4] = {0.f, 0.f, 0.f, 0.f};
    int i = 0;
    for (; i + 8 <= len; i += 8) {
        EdgeP p[8];
        float dv[8];
        uint h[8];
#pragma unroll
        for (int j = 0; j < 8; ++j) p[j] = ell[base + i + j];
#pragma unroll
        for (int j = 0; j < 8; ++j) {
            dv[j] = dinv[p[j].s];
            h[j] = *(const uint*)&hW[(size_t)p[j].s * HID + lane * 2];
        }
#pragma unroll
        for (int j = 0; j < 8; ++j) {
            float t = dv[j] * p[j].w;
            H2 hh; hh.u = h[j];
            float2 hf = __half22float2(hh.h2);
            ax[j & 3] = fmaf(t, hf.x, ax[j & 3]);
            ay[j & 3] = fmaf(t, hf.y, ay[j & 3]);
        }
    }
    for (; i < len; ++i) {
        EdgeP p = ell[base + i];
        float t = dinv[p.s] * p.w;
        H2 hh; hh.u = *(const uint*)&hW[(size_t)p.s * HID + lane * 2];
        float2 hf = __half22float2(hh.h2);
        ax[0] = fmaf(t, hf.x, ax[0]);
        ay[0] = fmaf(t, hf.y, ay[0]);
    }
    float sx = selfx + di * ((ax[0] + ax[1]) + (ax[2] + ax[3]));
    float sy = selfy + di * ((ay[0] + ay[1]) + (ay[2] + ay[3]));
    *(float2*)&S[(size_t)v * HID + lane * 2] = make_float2(selu_f(sx), selu_f(sy));
}

// ---------------- fused: layer-1 aggregation + SELU + (H1 @ W2) -> fp16 (4 nodes/block, ILP-8) ----
__global__ __launch_bounds__(256) void agg64_gemm2(
    const __half* __restrict__ hW, const float* __restrict__ S,
    const float* __restrict__ dinv, const int* __restrict__ cnt,
    const EdgeP* __restrict__ ell, int cap,
    const float* __restrict__ W2, __half* __restrict__ out16, int n) {
    __shared__ float sW[64 * 16];
    __shared__ float sh[4][64];
    int tid = threadIdx.x;
#pragma unroll
    for (int i = 0; i < 4; ++i) sW[i * 256 + tid] = W2[i * 256 + tid];

    int g = tid >> 6, f = tid & 63;
    int v = blockIdx.x * 4 + g;
    if (v < n) {
        float di = dinv[v];
        float self = S[(size_t)v * 64 + f] + di * di * __half2float(hW[(size_t)v * 64 + f]);
        size_t base = (size_t)v * cap;
        int len = cnt[v];
        float a[4] = {0.f, 0.f, 0.f, 0.f};
        int i = 0;
        for (; i + 8 <= len; i += 8) {
            EdgeP p[8];
            float dv[8];
            __half hv[8];
#pragma unroll
            for (int j = 0; j < 8; ++j) p[j] = ell[base + i + j];
#pragma unroll
            for (int j = 0; j < 8; ++j) {
                dv[j] = dinv[p[j].s];
                hv[j] = hW[(size_t)p[j].s * 64 + f];
            }
#pragma unroll
            for (int j = 0; j < 8; ++j)
                a[j & 3] = fmaf(dv[j] * p[j].w, __half2float(hv[j]), a[j & 3]);
        }
        for (; i < len; ++i) {
            EdgeP p = ell[base + i];
            a[0] = fmaf(dinv[p.s] * p.w, __half2float(hW[(size_t)p.s * 64 + f]), a[0]);
        }
        sh[g][f] = selu_f(self + di * ((a[0] + a[1]) + (a[2] + a[3])));
    }
    __syncthreads();
    if (v < n && f < 16) {
        float acc = 0.f;
#pragma unroll
        for (int k = 0; k < 64; ++k) acc = fmaf(sh[g][k], sW[k * 16 + f], acc);
        out16[(size_t)v * 16 + f] = __float2half(acc);
    }
}

// ---------------- layer 2 aggregation + selu + softmax (16 lanes per node, 16 nodes/block) ----
__global__ __launch_bounds__(256) void agg_softmax(
    const __half* __restrict__ hW, const float* __restrict__ b2,
    const float* __restrict__ dinv, const int* __restrict__ cnt,
    const EdgeP* __restrict__ ell, int cap,
    float* __restrict__ out, int n) {
    int tid = threadIdx.x;
    int g = tid >> 4, f = tid & 15;
    int v = blockIdx.x * 16 + g;
    if (v >= n) return;
    float di = dinv[v];
    float acc = b2[f] + di * di * __half2float(hW[(size_t)v * 16 + f]);
    size_t base = (size_t)v * cap;
    int len = cnt[v];
    float a[4] = {0.f, 0.f, 0.f, 0.f};
    int i = 0;
    for (; i + 4 <= len; i += 4) {
        EdgeP p[4];
        float dv[4];
        __half hv[4];
#pragma unroll
        for (int j = 0; j < 4; ++j) p[j] = ell[base + i + j];
#pragma unroll
        for (int j = 0; j < 4; ++j) {
            dv[j] = dinv[p[j].s];
            hv[j] = hW[(size_t)p[j].s * 16 + f];
        }
#pragma unroll
        for (int j = 0; j < 4; ++j)
            a[j] = fmaf(dv[j] * p[j].w, __half2float(hv[j]), a[j]);
    }
    for (; i < len; ++i) {
        EdgeP p = ell[base + i];
        a[0] = fmaf(dinv[p.s] * p.w, __half2float(hW[(size_t)p.s * 16 + f]), a[0]);
    }
    acc += di * ((a[0] + a[1]) + (a[2] + a[3]));
    acc = selu_f(acc);
    float m = acc;
    m = fmaxf(m, __shfl_xor(m, 1));
    m = fmaxf(m, __shfl_xor(m, 2));
    m = fmaxf(m, __shfl_xor(m, 4));
    m = fmaxf(m, __shfl_xor(m, 8));
    float ex = expf(acc - m);
    float sm = ex;
    sm += __shfl_xor(sm, 1);
    sm += __shfl_xor(sm, 2);
    sm += __shfl_xor(sm, 4);
    sm += __shfl_xor(sm, 8);
    out[(size_t)v * 16 + f] = ex / sm;
}

// ---------------- launch ----------------
extern "C" void kernel_launch(void* const* d_in, const int* in_sizes, int n_in,
                              void* d_out, int out_size, void* d_ws, size_t ws_size,
                              hipStream_t stream) {
    const float* x = (const float*)d_in[0];
    const int* ei = (const int*)d_in[1];   // int32 on device
    const float* ew = (const float*)d_in[2];
    const float* W0 = (const float*)d_in[3];
    const float* b0 = (const float*)d_in[4];
    const float* P0w = (const float*)d_in[5];
    const float* P0b = (const float*)d_in[6];
    const float* W1 = (const float*)d_in[7];
    const float* b1 = (const float*)d_in[8];
    const float* P1w = (const float*)d_in[9];
    const float* P1b = (const float*)d_in[10];
    const float* W2 = (const float*)d_in[11];
    const float* b2 = (const float*)d_in[12];
    float* out = (float*)d_out;
    const int n = in_sizes[0] / IN_DIM;
    const int E = in_sizes[2];
    const int NB = (n + NODES_PB - 1) / NODES_PB;

    auto al = [](size_t b) { return (b + 255) & ~(size_t)255; };
    // layout: cnt | dinv | bcur | WT0 | WT1 | bufA | bufB | ELL | R(records or bufC+bufD)
    size_t oCnt = 0;
    size_t oDinv = oCnt + al((size_t)n * 4);
    size_t oBcur = oDinv + al((size_t)n * 4);
    size_t oWT0 = oBcur + al((size_t)NBKT_MAX * 4);
    size_t oWT1 = oWT0 + al((size_t)IN_DIM * (HID * 2) * 2);
    size_t oA = oWT1 + al((size_t)HID * HID * 2);
    size_t oB = oA + al((size_t)n * HID * 2);
    size_t oEll = oB + al((size_t)n * HID * 4);
    size_t szEll96 = al((size_t)n * 96 * 8);
    size_t szEll80 = al((size_t)n * 80 * 8);
    size_t szRec = al((size_t)NB * BCAP * 8);
    size_t szCD = al((size_t)n * HID2 * 4) + al((size_t)n * 16 * 2);
    size_t szR = szRec > szCD ? szRec : szCD;

    int cap;
    int mode;  // 1 = two-phase sorted bin, 0 = direct ELL scatter fallback
    if (NB <= NBKT_MAX && oEll + szEll96 + szR <= ws_size) { cap = 96; mode = 1; }
    else if (oEll + szEll96 + szCD <= ws_size) { cap = 96; mode = 0; }
    else { cap = 80; mode = 0; }

    char* base = (char*)d_ws;
    int* cnt = (int*)(base + oCnt);
    float* dinv = (float*)(base + oDinv);
    int* bcur = (int*)(base + oBcur);
    __half* WT0 = (__half*)(base + oWT0);
    __half* WT1 = (__half*)(base + oWT1);
    __half* bufA = (__half*)(base + oA);
    float* bufB = (float*)(base + oB);
    EdgeP* ell = (EdgeP*)(base + oEll);
    size_t oR = oEll + (cap == 96 ? szEll96 : szEll80);
    EdgeP* recs = (EdgeP*)(base + oR);
    float* bufC = (float*)(base + oR);
    __half* bufD = (__half*)(base + oR + al((size_t)n * HID2 * 4));

    int gx = (n + 127) / 128;
    int gemmBlocks = gx * 2;
    int epb = (E + SB - 1) / SB;

    transpose_w<<<2 * HID, 128, 0, stream>>>(W0, P0w, WT0, IN_DIM, HID, HID);
    transpose_w<<<HID, 128, 0, stream>>>(W1, P1w, WT1, HID, HID2, HID2);

    if (mode == 1) {
        zero_ints<<<(NBKT_MAX + 255) / 256, 256, 0, stream>>>(bcur, NBKT_MAX);
        bin_gemm0<<<SB + gemmBlocks, 256, 0, stream>>>(
            x, WT0, b0, P0b, bufA, bufB, n, ei, ew, bcur, recs,
            E, cap, epb, SB, NB, 1);
        bucket_build<<<NB, NODES_PB, 0, stream>>>(recs, bcur, ell, cnt, dinv, n, cap);
    } else {
        zero_ints<<<(n + 255) / 256, 256, 0, stream>>>(cnt, n);
        bin_gemm0<<<SB + gemmBlocks, 256, 0, stream>>>(
            x, WT0, b0, P0b, bufA, bufB, n, ei, ew, cnt, ell,
            E, cap, epb, SB, NB, 0);
        int nbW = (n * 64 + 255) / 256;
        deg_dinv<<<nbW, 256, 0, stream>>>(ell, cnt, dinv, n, cap);
    }

    aggregate128<<<(n * 64 + 255) / 256, 256, 0, stream>>>(bufA, bufB, dinv, cnt, ell, cap, n);

    gemm1_fused<<<gx, 256, 0, stream>>>(bufB, WT1, b1, P1b, bufA, bufC, n);

    agg64_gemm2<<<(n + 3) / 4, 256, 0, stream>>>(bufA, bufC, dinv, cnt, ell, cap, W2, bufD, n);
    agg_softmax<<<(n + 15) / 16, 256, 0, stream>>>(bufD, b2, dinv, cnt, ell, cap, out, n);
}

// Round 12
// 487.459 us; speedup vs baseline: 1.0409x; 1.0409x over previous
//
#include <hip/hip_runtime.h>
#include <hip/hip_fp16.h>
#include <cmath>

#define IN_DIM 256
#define HID 128
#define HID2 64
#define SB 512        // bin-role blocks in the fused kernel
#define NODES_PB 256  // nodes per bucket (bin path)
#define NBKT_MAX 448  // max buckets supported by LDS scan arrays
#define BCAP 9216     // records per bucket region (mean 8184 + 11 sigma)
#define CHB 3328      // chunk size for bin-role sort (2 chunks for epb=6250)
#define CH 4096       // chunk size for bucket_build counting sort
#define SMEM_BIN (4 * NBKT_MAX * 4 + CHB * 9)  // 7168 + 29952 = 37120

struct __align__(8) EdgeP { int s; float w; };
union H4 { __half h[4]; uint2 u; };
union H2 { __half2 h2; uint u; };

using f16x8 = __attribute__((ext_vector_type(8))) _Float16;
using f32x4 = __attribute__((ext_vector_type(4))) float;

__device__ __forceinline__ float selu_f(float x) {
    const float scale = 1.0507009873554805f;
    const float alpha = 1.6732632423543772f;
    return x > 0.f ? scale * x : scale * alpha * expm1f(x);
}

// ---------------- small utility kernels ----------------

__global__ void zero_ints(int* p, int n) {
    int i = blockIdx.x * blockDim.x + threadIdx.x;
    if (i < n) p[i] = 0;
}

// WT[c][k] fp16 from B1 (K x C1) | B2 (K x C2); one block per output col c.
__global__ void transpose_w(const float* __restrict__ B1, const float* __restrict__ B2,
                            __half* __restrict__ WT, int K, int C1, int C2) {
    int c = blockIdx.x;
    for (int k = threadIdx.x; k < K; k += blockDim.x) {
        float v = (c < C1) ? B1[(size_t)k * C1 + c] : B2[(size_t)k * C2 + (c - C1)];
        WT[(size_t)c * K + k] = __float2half(v);
    }
}

// ---- fallback-path degree+dinv (one wave per node over ELL) ----
__global__ void deg_dinv(const EdgeP* __restrict__ ell, int* cnt, float* dinv, int n, int cap) {
    int wid = (blockIdx.x * blockDim.x + threadIdx.x) >> 6;
    int lane = threadIdx.x & 63;
    if (wid >= n) return;
    size_t base = (size_t)wid * cap;
    int len = min(cnt[wid], cap);
    float s = 0.f;
    for (int i = lane; i < len; i += 64) s += ell[base + i].w;
#pragma unroll
    for (int o = 32; o; o >>= 1) s += __shfl_xor(s, o);
    if (lane == 0) {
        dinv[wid] = rsqrtf(s + 1.0f);  // +1 = self-loop weight
        cnt[wid] = len;
    }
}

// exclusive scan of lds_in[0..nb) -> lds_out, executed by wave 0 (tid<64). nb <= 64*PER.
template <int PER>
__device__ __forceinline__ void wave0_excl_scan(const int* lds_in, int* lds_out, int nb, int tid) {
    if (tid < 64) {
        int r[PER];
        int sum = 0;
#pragma unroll
        for (int k = 0; k < PER; ++k) {
            int idx = tid * PER + k;
            int v = (idx < nb) ? lds_in[idx] : 0;
            r[k] = sum;
            sum += v;
        }
        int run = sum;
#pragma unroll
        for (int o = 1; o < 64; o <<= 1) {
            int t = __shfl_up(run, o);
            if (tid >= o) run += t;
        }
        int excl = run - sum;
#pragma unroll
        for (int k = 0; k < PER; ++k) {
            int idx = tid * PER + k;
            if (idx < nb) lds_out[idx] = excl + r[k];
        }
    }
}

// ---------------- fused role-split kernel ----------------
// Blocks [0,sblocks): bin role (mode=1): one global reserve per (block,bucket), then
// 2 chunks of {ILP-8 hist, scan, ILP-8 scatter-to-LDS sort, ILP-8 coalesced dump}.
// All streaming loops are explicitly 8-deep register-batched (latency, not throughput,
// dominates these blocks). mode=0: direct ELL scatter fallback.
// Remaining blocks: layer-0 GEMM via f16 MFMA.
__global__ __launch_bounds__(256) void bin_gemm0(
    const float* __restrict__ A, const __half* __restrict__ WT,
    const float* __restrict__ bias1, const float* __restrict__ bias2,
    __half* __restrict__ outA, float* __restrict__ outB, int M,
    const int* __restrict__ ei, const float* __restrict__ ew,
    int* cnt_or_bcur, EdgeP* __restrict__ dst_buf,
    int E, int cap, int epb, int sblocks, int nb, int mode) {
    const int tid = threadIdx.x;
    __shared__ __align__(16) char smem[SMEM_BIN];

    if ((int)blockIdx.x < sblocks) {
        int lo = blockIdx.x * epb;
        int hi = min(E, lo + epb);
        if (mode == 1) {
            int* gwcur = (int*)smem;                    // [NBKT_MAX]
            int* chist = gwcur + NBKT_MAX;              // [NBKT_MAX]
            int* coff = chist + NBKT_MAX;               // [NBKT_MAX]
            int* ccur = coff + NBKT_MAX;                // [NBKT_MAX]
            int* sortedS = ccur + NBKT_MAX;             // [CHB]
            float* sortedW = (float*)(sortedS + CHB);   // [CHB]
            unsigned char* smap = (unsigned char*)(sortedW + CHB);  // [CHB]

            // ---- phase A: full-range hist (ILP-8) -> one reserve per bucket ----
            for (int i = tid; i < nb; i += 256) chist[i] = 0;
            __syncthreads();
            for (int e0 = lo; e0 < hi; e0 += 2048) {
                int d[8];
#pragma unroll
                for (int j = 0; j < 8; ++j) {
                    int e = e0 + j * 256 + tid;
                    d[j] = (e < hi) ? ei[E + e] : -1;
                }
#pragma unroll
                for (int j = 0; j < 8; ++j)
                    if (d[j] >= 0) atomicAdd(&chist[d[j] >> 8], 1);
            }
            __syncthreads();
            for (int b = tid; b < nb; b += 256) {
                int h = chist[b];
                gwcur[b] = h ? atomicAdd(&cnt_or_bcur[b], h) : 0;
            }
            __syncthreads();

            // ---- phase B: 2 chunks of counting sort + coalesced dump ----
            for (int c0 = lo; c0 < hi; c0 += CHB) {
                int cn = min(CHB, hi - c0);
                for (int i = tid; i < nb; i += 256) chist[i] = 0;
                __syncthreads();
                for (int r0 = 0; r0 < cn; r0 += 2048) {
                    int d[8];
#pragma unroll
                    for (int j = 0; j < 8; ++j) {
                        int r = r0 + j * 256 + tid;
                        d[j] = (r < cn) ? ei[E + c0 + r] : -1;
                    }
#pragma unroll
                    for (int j = 0; j < 8; ++j)
                        if (d[j] >= 0) atomicAdd(&chist[d[j] >> 8], 1);
                }
                __syncthreads();
                wave0_excl_scan<7>(chist, coff, nb, tid);
                __syncthreads();
                for (int b = tid; b < nb; b += 256) ccur[b] = coff[b];
                __syncthreads();
                for (int r0 = 0; r0 < cn; r0 += 2048) {
                    int d[8], s8[8];
                    float w8[8];
#pragma unroll
                    for (int j = 0; j < 8; ++j) {
                        int r = r0 + j * 256 + tid;
                        d[j] = -1;
                        if (r < cn) {
                            int e = c0 + r;
                            d[j] = ei[E + e];
                            s8[j] = ei[e];
                            w8[j] = ew[e];
                        }
                    }
#pragma unroll
                    for (int j = 0; j < 8; ++j)
                        if (d[j] >= 0) {
                            int b = d[j] >> 8;
                            int slot = atomicAdd(&ccur[b], 1);
                            sortedS[slot] = (s8[j] << 8) | (d[j] & 255) | ((b >> 8) << 25);
                            sortedW[slot] = w8[j];
                            smap[slot] = (unsigned char)(b & 255);
                        }
                }
                __syncthreads();
                for (int i0 = 0; i0 < cn; i0 += 2048) {
                    int key[8], bb[8];
                    float wv[8];
#pragma unroll
                    for (int j = 0; j < 8; ++j) {
                        int i = i0 + j * 256 + tid;
                        bb[j] = -1;
                        if (i < cn) {
                            key[j] = sortedS[i];
                            wv[j] = sortedW[i];
                            bb[j] = smap[i] | (((key[j] >> 25) & 1) << 8);
                        }
                    }
#pragma unroll
                    for (int j = 0; j < 8; ++j)
                        if (bb[j] >= 0) {
                            int i = i0 + j * 256 + tid;
                            int addr = gwcur[bb[j]] + (i - coff[bb[j]]);
                            if (addr < BCAP) {
                                EdgeP p; p.s = key[j] & 0x01FFFFFF; p.w = wv[j];
                                dst_buf[(size_t)bb[j] * BCAP + addr] = p;
                            }
                        }
                }
                __syncthreads();
                for (int b = tid; b < nb; b += 256) gwcur[b] += chist[b];
                __syncthreads();
            }
        } else {
            for (int base = lo; base < hi; base += 2048) {
                int r[8], c[8], pos[8];
                float wv[8];
#pragma unroll
                for (int j = 0; j < 8; ++j) {
                    int e = base + j * 256 + tid;
                    c[j] = -1;
                    if (e < hi) { r[j] = ei[e]; c[j] = ei[E + e]; wv[j] = ew[e]; }
                }
#pragma unroll
                for (int j = 0; j < 8; ++j)
                    if (c[j] >= 0) pos[j] = atomicAdd(&cnt_or_bcur[c[j]], 1);
#pragma unroll
                for (int j = 0; j < 8; ++j)
                    if (c[j] >= 0 && pos[j] < cap) {
                        EdgeP p; p.s = r[j]; p.w = wv[j];
                        dst_buf[(size_t)c[j] * cap + pos[j]] = p;
                    }
            }
        }
        return;
    }

    // ---- MFMA GEMM role: K=256 ----
    __half* sA16 = (__half*)smem;            // [128*40]
    __half* sB16 = (__half*)(smem + 10240);  // [128*40]
    const int bid = blockIdx.x - sblocks;
    const int m0 = (bid >> 1) * 128;
    const int n0 = (bid & 1) * 128;
    const int lane = tid & 63;
    const int wv = tid >> 6;
    const int wr = (wv >> 1) * 64;
    const int wc = (wv & 1) * 64;
    const int lr = lane & 15, lk = lane >> 4;

    f32x4 zero = {0.f, 0.f, 0.f, 0.f};
    f32x4 acc[4][4];
#pragma unroll
    for (int i = 0; i < 4; ++i)
#pragma unroll
        for (int j = 0; j < 4; ++j) acc[i][j] = zero;

    for (int k0 = 0; k0 < IN_DIM; k0 += 32) {
#pragma unroll
        for (int p = 0; p < 4; ++p) {
            int f4 = p * 256 + tid;
            int r = f4 >> 3;
            int kk = (f4 & 7) << 2;
            int row = m0 + r;
            float4 v = make_float4(0.f, 0.f, 0.f, 0.f);
            if (row < M) v = *(const float4*)(A + (size_t)row * IN_DIM + k0 + kk);
            H4 h;
            h.h[0] = __float2half(v.x); h.h[1] = __float2half(v.y);
            h.h[2] = __float2half(v.z); h.h[3] = __float2half(v.w);
            *(uint2*)&sA16[r * 40 + kk] = h.u;
        }
#pragma unroll
        for (int p = 0; p < 2; ++p) {
            int f = p * 256 + tid;
            int c = f >> 2;
            int kc = (f & 3) << 3;
            *(uint4*)&sB16[c * 40 + kc] =
                *(const uint4*)(WT + (size_t)(n0 + c) * IN_DIM + k0 + kc);
        }
        __syncthreads();
        f16x8 af[4], bf[4];
#pragma unroll
        for (int i = 0; i < 4; ++i)
            af[i] = *(const f16x8*)&sA16[(wr + i * 16 + lr) * 40 + lk * 8];
#pragma unroll
        for (int j = 0; j < 4; ++j)
            bf[j] = *(const f16x8*)&sB16[(wc + j * 16 + lr) * 40 + lk * 8];
#pragma unroll
        for (int i = 0; i < 4; ++i)
#pragma unroll
            for (int j = 0; j < 4; ++j)
                acc[i][j] = __builtin_amdgcn_mfma_f32_16x16x32_f16(af[i], bf[j], acc[i][j], 0, 0, 0);
        __syncthreads();
    }

    float bs[4];
    if (n0 != 0) {
#pragma unroll
        for (int j = 0; j < 4; ++j) {
            int c = wc + j * 16 + lr;
            bs[j] = bias1[c] + bias2[c];
        }
    }
#pragma unroll
    for (int i = 0; i < 4; ++i) {
        int rowb = m0 + wr + i * 16 + lk * 4;
#pragma unroll
        for (int j = 0; j < 4; ++j) {
            int col = wc + j * 16 + lr;
#pragma unroll
            for (int r = 0; r < 4; ++r) {
                int row = rowb + r;
                if (row < M) {
                    if (n0 == 0)
                        outA[(size_t)row * HID + col] = __float2half(acc[i][j][r]);
                    else
                        outB[(size_t)row * HID + col] = acc[i][j][r] + bs[j];
                }
            }
        }
    }
}

// ---------------- phase-2: per-bucket ELL build via in-LDS counting sort (ILP-8) ----------------
__global__ __launch_bounds__(256) void bucket_build(
    const EdgeP* __restrict__ recs, const int* __restrict__ bcur,
    EdgeP* __restrict__ ell, int* __restrict__ cnt, float* __restrict__ dinv,
    int n, int cap) {
    __shared__ int lcnt[NODES_PB];
    __shared__ float ldeg[NODES_PB];
    __shared__ int chist[NODES_PB];
    __shared__ int coff[NODES_PB];
    __shared__ int ccur[NODES_PB];
    __shared__ __align__(8) int sortedS[CH];
    __shared__ float sortedW[CH];
    __shared__ unsigned char cmap[CH];
    int b = blockIdx.x, tid = threadIdx.x;
    lcnt[tid] = 0;
    ldeg[tid] = 0.f;
    __syncthreads();
    int m = min(bcur[b], BCAP);
    const EdgeP* rbase = recs + (size_t)b * BCAP;
    for (int c0 = 0; c0 < m; c0 += CH) {
        int cn = min(CH, m - c0);
        chist[tid] = 0;
        __syncthreads();
        for (int i0 = 0; i0 < cn; i0 += 2048) {
            EdgeP p[8];
            int ok[8];
#pragma unroll
            for (int j = 0; j < 8; ++j) {
                int i = i0 + j * 256 + tid;
                ok[j] = (i < cn);
                if (ok[j]) p[j] = rbase[c0 + i];
            }
#pragma unroll
            for (int j = 0; j < 8; ++j)
                if (ok[j]) {
                    int dl = p[j].s & 255;
                    atomicAdd(&chist[dl], 1);
                    atomicAdd(&ldeg[dl], p[j].w);
                }
        }
        __syncthreads();
        wave0_excl_scan<4>(chist, coff, NODES_PB, tid);
        __syncthreads();
        ccur[tid] = coff[tid];
        __syncthreads();
        for (int i0 = 0; i0 < cn; i0 += 2048) {
            EdgeP p[8];
            int ok[8];
#pragma unroll
            for (int j = 0; j < 8; ++j) {
                int i = i0 + j * 256 + tid;
                ok[j] = (i < cn);
                if (ok[j]) p[j] = rbase[c0 + i];
            }
#pragma unroll
            for (int j = 0; j < 8; ++j)
                if (ok[j]) {
                    int dl = p[j].s & 255;
                    int slot = atomicAdd(&ccur[dl], 1);
                    sortedS[slot] = p[j].s >> 8;
                    sortedW[slot] = p[j].w;
                    cmap[slot] = (unsigned char)dl;
                }
        }
        __syncthreads();
        for (int i0 = 0; i0 < cn; i0 += 2048) {
            int s8[8], dl8[8];
            float w8[8];
#pragma unroll
            for (int j = 0; j < 8; ++j) {
                int i = i0 + j * 256 + tid;
                dl8[j] = -1;
                if (i < cn) {
                    s8[j] = sortedS[i];
                    w8[j] = sortedW[i];
                    dl8[j] = cmap[i];
                }
            }
#pragma unroll
            for (int j = 0; j < 8; ++j)
                if (dl8[j] >= 0) {
                    int i = i0 + j * 256 + tid;
                    int rank = lcnt[dl8[j]] + (i - coff[dl8[j]]);
                    if (rank < cap) {
                        EdgeP q; q.s = s8[j]; q.w = w8[j];
                        ell[((size_t)(b * NODES_PB + dl8[j])) * cap + rank] = q;
                    }
                }
        }
        __syncthreads();
        lcnt[tid] += chist[tid];
        __syncthreads();
    }
    int v = b * NODES_PB + tid;
    if (v < n) {
        cnt[v] = min(lcnt[tid], cap);
        dinv[v] = rsqrtf(ldeg[tid] + 1.0f);
    }
}

// ---------------- layer-1 GEMM via f16 MFMA ----------------
__global__ __launch_bounds__(256) void gemm1_fused(
    const float* __restrict__ A, const __half* __restrict__ WT,
    const float* __restrict__ bias1, const float* __restrict__ bias2,
    __half* __restrict__ outA, float* __restrict__ outB, int M) {
    const int tid = threadIdx.x;
    __shared__ __align__(16) __half sA16[128 * 40];
    __shared__ __align__(16) __half sB16[128 * 40];
    const int m0 = blockIdx.x * 128;
    const int lane = tid & 63;
    const int wv = tid >> 6;
    const int wr = (wv >> 1) * 64;
    const int wc = (wv & 1) * 64;
    const int lr = lane & 15, lk = lane >> 4;

    f32x4 zero = {0.f, 0.f, 0.f, 0.f};
    f32x4 acc[4][4];
#pragma unroll
    for (int i = 0; i < 4; ++i)
#pragma unroll
        for (int j = 0; j < 4; ++j) acc[i][j] = zero;

    for (int k0 = 0; k0 < HID; k0 += 32) {
#pragma unroll
        for (int p = 0; p < 4; ++p) {
            int f4 = p * 256 + tid;
            int r = f4 >> 3;
            int kk = (f4 & 7) << 2;
            int row = m0 + r;
            float4 v = make_float4(0.f, 0.f, 0.f, 0.f);
            if (row < M) v = *(const float4*)(A + (size_t)row * HID + k0 + kk);
            H4 h;
            h.h[0] = __float2half(v.x); h.h[1] = __float2half(v.y);
            h.h[2] = __float2half(v.z); h.h[3] = __float2half(v.w);
            *(uint2*)&sA16[r * 40 + kk] = h.u;
        }
#pragma unroll
        for (int p = 0; p < 2; ++p) {
            int f = p * 256 + tid;
            int c = f >> 2;
            int kc = (f & 3) << 3;
            *(uint4*)&sB16[c * 40 + kc] =
                *(const uint4*)(WT + (size_t)c * HID + k0 + kc);
        }
        __syncthreads();
        f16x8 af[4], bf[4];
#pragma unroll
        for (int i = 0; i < 4; ++i)
            af[i] = *(const f16x8*)&sA16[(wr + i * 16 + lr) * 40 + lk * 8];
#pragma unroll
        for (int j = 0; j < 4; ++j)
            bf[j] = *(const f16x8*)&sB16[(wc + j * 16 + lr) * 40 + lk * 8];
#pragma unroll
        for (int i = 0; i < 4; ++i)
#pragma unroll
            for (int j = 0; j < 4; ++j)
                acc[i][j] = __builtin_amdgcn_mfma_f32_16x16x32_f16(af[i], bf[j], acc[i][j], 0, 0, 0);
        __syncthreads();
    }

    float bs[4];
    if (wc != 0) {
#pragma unroll
        for (int j = 0; j < 4; ++j) {
            int c = wc + j * 16 + lr - HID2;
            bs[j] = bias1[c] + bias2[c];
        }
    }
#pragma unroll
    for (int i = 0; i < 4; ++i) {
        int rowb = m0 + wr + i * 16 + lk * 4;
#pragma unroll
        for (int j = 0; j < 4; ++j) {
            int col = wc + j * 16 + lr;
#pragma unroll
            for (int r = 0; r < 4; ++r) {
                int row = rowb + r;
                if (row < M) {
                    if (wc == 0)
                        outA[(size_t)row * HID2 + col] = __float2half(acc[i][j][r]);
                    else
                        outB[(size_t)row * HID2 + (col - HID2)] = acc[i][j][r] + bs[j];
                }
            }
        }
    }
}

// ---------------- aggregation F=128: ONE WAVE per node, half2 per lane, ILP-8 ----------------
__global__ __launch_bounds__(256) void aggregate128(
    const __half* __restrict__ hW, float* __restrict__ S,
    const float* __restrict__ dinv, const int* __restrict__ cnt,
    const EdgeP* __restrict__ ell, int cap, int n) {
    int v = (blockIdx.x * 256 + threadIdx.x) >> 6;
    int lane = threadIdx.x & 63;
    if (v >= n) return;
    float di = dinv[v];
    float2 sv = *(const float2*)&S[(size_t)v * HID + lane * 2];
    H2 selfh; selfh.u = *(const uint*)&hW[(size_t)v * HID + lane * 2];
    float2 selff = __half22float2(selfh.h2);
    float selfx = sv.x + di * di * selff.x;
    float selfy = sv.y + di * di * selff.y;

    size_t base = (size_t)v * cap;
    int len = cnt[v];
    float ax[4] = {0.f, 0.f, 0.f, 0.f};
    float ay[4] = {0.f, 0.f, 0.f, 0.f};
    int i = 0;
    for (; i + 8 <= len; i += 8) {
        EdgeP p[8];
        float dv[8];
        uint h[8];
#pragma unroll
        for (int j = 0; j < 8; ++j) p[j] = ell[base + i + j];
#pragma unroll
        for (int j = 0; j < 8; ++j) {
            dv[j] = dinv[p[j].s];
            h[j] = *(const uint*)&hW[(size_t)p[j].s * HID + lane * 2];
        }
#pragma unroll
        for (int j = 0; j < 8; ++j) {
            float t = dv[j] * p[j].w;
            H2 hh; hh.u = h[j];
            float2 hf = __half22float2(hh.h2);
            ax[j & 3] = fmaf(t, hf.x, ax[j & 3]);
            ay[j & 3] = fmaf(t, hf.y, ay[j & 3]);
        }
    }
    for (; i < len; ++i) {
        EdgeP p = ell[base + i];
        float t = dinv[p.s] * p.w;
        H2 hh; hh.u = *(const uint*)&hW[(size_t)p.s * HID + lane * 2];
        float2 hf = __half22float2(hh.h2);
        ax[0] = fmaf(t, hf.x, ax[0]);
        ay[0] = fmaf(t, hf.y, ay[0]);
    }
    float sx = selfx + di * ((ax[0] + ax[1]) + (ax[2] + ax[3]));
    float sy = selfy + di * ((ay[0] + ay[1]) + (ay[2] + ay[3]));
    *(float2*)&S[(size_t)v * HID + lane * 2] = make_float2(selu_f(sx), selu_f(sy));
}

// ---------------- fused: layer-1 aggregation + SELU + (H1 @ W2) -> fp16 (4 nodes/block, ILP-8) ----
__global__ __launch_bounds__(256) void agg64_gemm2(
    const __half* __restrict__ hW, const float* __restrict__ S,
    const float* __restrict__ dinv, const int* __restrict__ cnt,
    const EdgeP* __restrict__ ell, int cap,
    const float* __restrict__ W2, __half* __restrict__ out16, int n) {
    __shared__ float sW[64 * 16];
    __shared__ float sh[4][64];
    int tid = threadIdx.x;
#pragma unroll
    for (int i = 0; i < 4; ++i) sW[i * 256 + tid] = W2[i * 256 + tid];

    int g = tid >> 6, f = tid & 63;
    int v = blockIdx.x * 4 + g;
    if (v < n) {
        float di = dinv[v];
        float self = S[(size_t)v * 64 + f] + di * di * __half2float(hW[(size_t)v * 64 + f]);
        size_t base = (size_t)v * cap;
        int len = cnt[v];
        float a[4] = {0.f, 0.f, 0.f, 0.f};
        int i = 0;
        for (; i + 8 <= len; i += 8) {
            EdgeP p[8];
            float dv[8];
            __half hv[8];
#pragma unroll
            for (int j = 0; j < 8; ++j) p[j] = ell[base + i + j];
#pragma unroll
            for (int j = 0; j < 8; ++j) {
                dv[j] = dinv[p[j].s];
                hv[j] = hW[(size_t)p[j].s * 64 + f];
            }
#pragma unroll
            for (int j = 0; j < 8; ++j)
                a[j & 3] = fmaf(dv[j] * p[j].w, __half2float(hv[j]), a[j & 3]);
        }
        for (; i < len; ++i) {
            EdgeP p = ell[base + i];
            a[0] = fmaf(dinv[p.s] * p.w, __half2float(hW[(size_t)p.s * 64 + f]), a[0]);
        }
        sh[g][f] = selu_f(self + di * ((a[0] + a[1]) + (a[2] + a[3])));
    }
    __syncthreads();
    if (v < n && f < 16) {
        float acc = 0.f;
#pragma unroll
        for (int k = 0; k < 64; ++k) acc = fmaf(sh[g][k], sW[k * 16 + f], acc);
        out16[(size_t)v * 16 + f] = __float2half(acc);
    }
}

// ---------------- layer 2 aggregation + selu + softmax (16 lanes per node, 16 nodes/block) ----
__global__ __launch_bounds__(256) void agg_softmax(
    const __half* __restrict__ hW, const float* __restrict__ b2,
    const float* __restrict__ dinv, const int* __restrict__ cnt,
    const EdgeP* __restrict__ ell, int cap,
    float* __restrict__ out, int n) {
    int tid = threadIdx.x;
    int g = tid >> 4, f = tid & 15;
    int v = blockIdx.x * 16 + g;
    if (v >= n) return;
    float di = dinv[v];
    float acc = b2[f] + di * di * __half2float(hW[(size_t)v * 16 + f]);
    size_t base = (size_t)v * cap;
    int len = cnt[v];
    float a[4] = {0.f, 0.f, 0.f, 0.f};
    int i = 0;
    for (; i + 4 <= len; i += 4) {
        EdgeP p[4];
        float dv[4];
        __half hv[4];
#pragma unroll
        for (int j = 0; j < 4; ++j) p[j] = ell[base + i + j];
#pragma unroll
        for (int j = 0; j < 4; ++j) {
            dv[j] = dinv[p[j].s];
            hv[j] = hW[(size_t)p[j].s * 16 + f];
        }
#pragma unroll
        for (int j = 0; j < 4; ++j)
            a[j] = fmaf(dv[j] * p[j].w, __half2float(hv[j]), a[j]);
    }
    for (; i < len; ++i) {
        EdgeP p = ell[base + i];
        a[0] = fmaf(dinv[p.s] * p.w, __half2float(hW[(size_t)p.s * 16 + f]), a[0]);
    }
    acc += di * ((a[0] + a[1]) + (a[2] + a[3]));
    acc = selu_f(acc);
    float m = acc;
    m = fmaxf(m, __shfl_xor(m, 1));
    m = fmaxf(m, __shfl_xor(m, 2));
    m = fmaxf(m, __shfl_xor(m, 4));
    m = fmaxf(m, __shfl_xor(m, 8));
    float ex = expf(acc - m);
    float sm = ex;
    sm += __shfl_xor(sm, 1);
    sm += __shfl_xor(sm, 2);
    sm += __shfl_xor(sm, 4);
    sm += __shfl_xor(sm, 8);
    out[(size_t)v * 16 + f] = ex / sm;
}

// ---------------- launch ----------------
extern "C" void kernel_launch(void* const* d_in, const int* in_sizes, int n_in,
                              void* d_out, int out_size, void* d_ws, size_t ws_size,
                              hipStream_t stream) {
    const float* x = (const float*)d_in[0];
    const int* ei = (const int*)d_in[1];   // int32 on device
    const float* ew = (const float*)d_in[2];
    const float* W0 = (const float*)d_in[3];
    const float* b0 = (const float*)d_in[4];
    const float* P0w = (const float*)d_in[5];
    const float* P0b = (const float*)d_in[6];
    const float* W1 = (const float*)d_in[7];
    const float* b1 = (const float*)d_in[8];
    const float* P1w = (const float*)d_in[9];
    const float* P1b = (const float*)d_in[10];
    const float* W2 = (const float*)d_in[11];
    const float* b2 = (const float*)d_in[12];
    float* out = (float*)d_out;
    const int n = in_sizes[0] / IN_DIM;
    const int E = in_sizes[2];
    const int NB = (n + NODES_PB - 1) / NODES_PB;

    auto al = [](size_t b) { return (b + 255) & ~(size_t)255; };
    size_t oCnt = 0;
    size_t oDinv = oCnt + al((size_t)n * 4);
    size_t oBcur = oDinv + al((size_t)n * 4);
    size_t oWT0 = oBcur + al((size_t)NBKT_MAX * 4);
    size_t oWT1 = oWT0 + al((size_t)IN_DIM * (HID * 2) * 2);
    size_t oA = oWT1 + al((size_t)HID * HID * 2);
    size_t oB = oA + al((size_t)n * HID * 2);
    size_t oEll = oB + al((size_t)n * HID * 4);
    size_t szEll96 = al((size_t)n * 96 * 8);
    size_t szEll80 = al((size_t)n * 80 * 8);
    size_t szRec = al((size_t)NB * BCAP * 8);
    size_t szCD = al((size_t)n * HID2 * 4) + al((size_t)n * 16 * 2);
    size_t szR = szRec > szCD ? szRec : szCD;

    int cap;
    int mode;
    if (NB <= NBKT_MAX && oEll + szEll96 + szR <= ws_size) { cap = 96; mode = 1; }
    else if (oEll + szEll96 + szCD <= ws_size) { cap = 96; mode = 0; }
    else { cap = 80; mode = 0; }

    char* base = (char*)d_ws;
    int* cnt = (int*)(base + oCnt);
    float* dinv = (float*)(base + oDinv);
    int* bcur = (int*)(base + oBcur);
    __half* WT0 = (__half*)(base + oWT0);
    __half* WT1 = (__half*)(base + oWT1);
    __half* bufA = (__half*)(base + oA);
    float* bufB = (float*)(base + oB);
    EdgeP* ell = (EdgeP*)(base + oEll);
    size_t oR = oEll + (cap == 96 ? szEll96 : szEll80);
    EdgeP* recs = (EdgeP*)(base + oR);
    float* bufC = (float*)(base + oR);
    __half* bufD = (__half*)(base + oR + al((size_t)n * HID2 * 4));

    int gx = (n + 127) / 128;
    int gemmBlocks = gx * 2;
    int epb = (E + SB - 1) / SB;

    transpose_w<<<2 * HID, 128, 0, stream>>>(W0, P0w, WT0, IN_DIM, HID, HID);
    transpose_w<<<HID, 128, 0, stream>>>(W1, P1w, WT1, HID, HID2, HID2);

    if (mode == 1) {
        zero_ints<<<(NBKT_MAX + 255) / 256, 256, 0, stream>>>(bcur, NBKT_MAX);
        bin_gemm0<<<SB + gemmBlocks, 256, 0, stream>>>(
            x, WT0, b0, P0b, bufA, bufB, n, ei, ew, bcur, recs,
            E, cap, epb, SB, NB, 1);
        bucket_build<<<NB, NODES_PB, 0, stream>>>(recs, bcur, ell, cnt, dinv, n, cap);
    } else {
        zero_ints<<<(n + 255) / 256, 256, 0, stream>>>(cnt, n);
        bin_gemm0<<<SB + gemmBlocks, 256, 0, stream>>>(
            x, WT0, b0, P0b, bufA, bufB, n, ei, ew, cnt, ell,
            E, cap, epb, SB, NB, 0);
        int nbW = (n * 64 + 255) / 256;
        deg_dinv<<<nbW, 256, 0, stream>>>(ell, cnt, dinv, n, cap);
    }

    aggregate128<<<(n * 64 + 255) / 256, 256, 0, stream>>>(bufA, bufB, dinv, cnt, ell, cap, n);

    gemm1_fused<<<gx, 256, 0, stream>>>(bufB, WT1, b1, P1b, bufA, bufC, n);

    agg64_gemm2<<<(n + 3) / 4, 256, 0, stream>>>(bufA, bufC, dinv, cnt, ell, cap, W2, bufD, n);
    agg_softmax<<<(n + 15) / 16, 256, 0, stream>>>(bufD, b2, dinv, cnt, ell, cap, out, n);
}